// Round 3
// baseline (92.045 us; speedup 1.0000x reference)
//
#include <hip/hip_runtime.h>
#include <math.h>

typedef _Float16 f16;
typedef __attribute__((ext_vector_type(8))) _Float16 f16x8;
typedef __attribute__((ext_vector_type(16))) float f32x16;

// sat (128,4,64,16) f32, grd (128,4,64,16) f32
// out (f32): sat 524288 | grd 524288 | distance[g][s] 16384 | orien[s][g] 16384
#define DIST_OFF  1048576
#define ORI_OFF   1064960
#define SATP_STR  72      // f16 elems per satP row (144 B = 36 dwords -> conflict-free)

#define MFMA(a,b,c) __builtin_amdgcn_mfma_f32_32x32x16_f16((a),(b),(c),0,0,0)

// Convert 8 consecutive f32 (two float4) into f16 hi + f16 lo fragments.
// Bit-identical to the old prep_k path: hv=(f16)v; lv=(f16)(v-(float)hv).
__device__ inline void cvt8(float4 a, float4 b, f16x8* hi, f16x8* lo) {
    float va[8] = {a.x, a.y, a.z, a.w, b.x, b.y, b.z, b.w};
    f16x8 h, l;
    #pragma unroll
    for (int e = 0; e < 8; ++e) {
        f16 hv = (f16)va[e];
        h[e] = hv;
        l[e] = (f16)(va[e] - (float)hv);
    }
    *hi = h; *lo = l;
}

// ---- single fused kernel: block=(s, g-half64), 8 waves = 8-way K split ----
// B fragments load DIRECTLY from raw grd: fragment (8 consecutive k, fixed g)
// == grd[g, t&3, t>>2, 8*half .. +8) == 8 contiguous floats. No prep needed.
__global__ __launch_bounds__(512, 2) void corr_k(const float* __restrict__ sat,
                                                 const float* __restrict__ grd,
                                                 float* __restrict__ out,
                                                 const float4* __restrict__ satIn,
                                                 const float4* __restrict__ grdIn,
                                                 float4* __restrict__ out4) {
    __shared__ __align__(16) unsigned char smem[131072];  // satP (36.6KB) then red (128KB)
    __shared__ float wred[8];
    __shared__ float rnormS;
    __shared__ float pBest[512];
    __shared__ int   pIdx[512];
    f16* sH = (f16*)smem;                 // [w' 0..126][hc 0..63], stride 72
    f16* sL = sH + 127 * SATP_STR;
    float* red = (float*)smem;            // [kh 8][j 64][g 64]

    const int tid = threadIdx.x;
    const int s  = blockIdx.x >> 1;
    const int gh = blockIdx.x & 1;
    const int wave = tid >> 6, lane = tid & 63;
    const int m = lane & 31, half = lane >> 5;

    // ---- stage satP hi/lo (doubled along w) + ||sat[s]||^2  (round-0 exact) ----
    const float* satS = sat + s * 4096;
    float ssq = 0.f;
    #pragma unroll
    for (int r = 0; r < 8; ++r) {
        int idx = r * 512 + tid;
        float v = satS[idx];
        int h = idx >> 10, w = (idx >> 4) & 63, c = idx & 15;
        int col = h * 16 + c;
        f16 hv = (f16)v, lv = (f16)(v - (float)hv);
        sH[w * SATP_STR + col] = hv;
        sL[w * SATP_STR + col] = lv;
        if (w < 63) { sH[(w + 64) * SATP_STR + col] = hv; sL[(w + 64) * SATP_STR + col] = lv; }
        ssq += v * v;
    }
    #pragma unroll
    for (int off = 32; off > 0; off >>= 1) ssq += __shfl_down(ssq, off, 64);
    if (lane == 0) wred[wave] = ssq;
    __syncthreads();
    if (tid == 0) {
        float t = 0.f;
        #pragma unroll
        for (int i = 0; i < 8; ++i) t += wred[i];
        rnormS = 1.f / fmaxf(sqrtf(t), 1e-12f);
    }

    // ---- K-loop: kh = wave, 32 k-tiles of 16; double buffer; direct-B from grd ----
    const f16* A0h = sH + m * SATP_STR + half * 8;
    const f16* A0l = sL + m * SATP_STR + half * 8;
    // B base: g = gh*64 + m (and +32); k0 = 16t + 8*half -> h=t&3, w=t>>2, c0=8*half
    const float* BgA = grd + (gh * 64 + m) * 4096 + half * 8;
    const float* BgB = BgA + 32 * 4096;

    f32x16 z;
    #pragma unroll
    for (int r = 0; r < 16; ++r) z[r] = 0.f;
    f32x16 h00 = z, h01 = z, h10 = z, h11 = z, x00 = z, x01 = z, x10 = z, x11 = z;

    f16x8 ah[2][2], al[2][2], bh[2][2], bl[2][2];

#define LOADA(p, t) { \
    int tc = (t) > 255 ? 255 : (t); \
    int ao = (tc >> 2) * SATP_STR + (tc & 3) * 16; \
    ah[p][0] = *(const f16x8*)(A0h + ao); \
    ah[p][1] = *(const f16x8*)(A0h + ao + 32 * SATP_STR); \
    al[p][0] = *(const f16x8*)(A0l + ao); \
    al[p][1] = *(const f16x8*)(A0l + ao + 32 * SATP_STR); }

#define LOADB(p, t) { \
    int tc = (t) > 255 ? 255 : (t); \
    int fo = (tc & 3) * 1024 + (tc >> 2) * 16; \
    float4 u0 = *(const float4*)(BgA + fo); \
    float4 u1 = *(const float4*)(BgA + fo + 4); \
    float4 w0 = *(const float4*)(BgB + fo); \
    float4 w1 = *(const float4*)(BgB + fo + 4); \
    cvt8(u0, u1, &bh[p][0], &bl[p][0]); \
    cvt8(w0, w1, &bh[p][1], &bl[p][1]); }

#define STEP(p) { \
    h00 = MFMA(ah[p][0], bh[p][0], h00); \
    h01 = MFMA(ah[p][0], bh[p][1], h01); \
    h10 = MFMA(ah[p][1], bh[p][0], h10); \
    h11 = MFMA(ah[p][1], bh[p][1], h11); \
    x00 = MFMA(ah[p][0], bl[p][0], x00); x00 = MFMA(al[p][0], bh[p][0], x00); \
    x01 = MFMA(ah[p][0], bl[p][1], x01); x01 = MFMA(al[p][0], bh[p][1], x01); \
    x10 = MFMA(ah[p][1], bl[p][0], x10); x10 = MFMA(al[p][1], bh[p][0], x10); \
    x11 = MFMA(ah[p][1], bl[p][1], x11); x11 = MFMA(al[p][1], bh[p][1], x11); }

    const int t0 = wave * 32;
    LOADA(0, t0) LOADB(0, t0)
    #pragma unroll 4
    for (int t = t0; t < t0 + 32; t += 2) {
        LOADA(1, t + 1) LOADB(1, t + 1)
        STEP(0)
        LOADA(0, t + 2) LOADB(0, t + 2)   // clamped; last iteration's extra load unused
        STEP(1)
    }
    h00 = h00 + x00; h01 = h01 + x01; h10 = h10 + x10; h11 = h11 + x11;

    // ---- flat 8-partial reduce (satP dead; red reuses smem) ----
    __syncthreads();
    float* rw = red + wave * 4096;
    #pragma unroll
    for (int r = 0; r < 16; ++r) {
        int j0 = (r & 3) + 8 * (r >> 2) + 4 * half;      // j within 32-tile
        rw[j0 * 64 + m]             = h00[r];
        rw[j0 * 64 + 32 + m]        = h01[r];
        rw[(j0 + 32) * 64 + m]      = h10[r];
        rw[(j0 + 32) * 64 + 32 + m] = h11[r];
    }
    __syncthreads();
    #pragma unroll
    for (int i = 0; i < 8; ++i) {
        int c = i * 512 + tid;                           // j = c>>6, g = c&63
        float v = red[c]         + red[c + 4096]  + red[c + 8192]  + red[c + 12288]
                + red[c + 16384] + red[c + 20480] + red[c + 24576] + red[c + 28672];
        red[c] = v;                                      // own-cell only: race-free
    }
    __syncthreads();

    // ---- argmax over j, parallel with exact first-occurrence tie semantics ----
    {
        int g = tid & 63, jq = tid >> 6;
        int jb = jq * 8;
        float best = red[jb * 64 + g];
        int bj = jb;
        #pragma unroll
        for (int jj = 1; jj < 8; ++jj) {
            float v = red[(jb + jj) * 64 + g];
            if (v > best) { best = v; bj = jb + jj; }
        }
        pBest[tid] = best; pIdx[tid] = bj;
    }
    __syncthreads();
    if (tid < 64) {
        int g = tid;
        float best = pBest[g]; int bj = pIdx[g];
        #pragma unroll
        for (int jq = 1; jq < 8; ++jq) {                 // ascending jq: keeps earliest j on ties
            float v = pBest[jq * 64 + g];
            if (v > best) { best = v; bj = pIdx[jq * 64 + g]; }
        }
        float dot = best * rnormS;
        int gg = gh * 64 + g;
        out[DIST_OFF + gg * 128 + s] = 2.f - 2.f * dot;
        out[ORI_OFF + s * 128 + gg]  = (float)bj;
    }

    // ---- fused passthrough copies (256 blocks x 512 thr = 131072 float4 each) ----
    {
        int i = blockIdx.x * 512 + tid;
        out4[i] = satIn[i];
        out4[131072 + i] = grdIn[i];
    }
}

extern "C" void kernel_launch(void* const* d_in, const int* in_sizes, int n_in,
                              void* d_out, int out_size, void* d_ws, size_t ws_size,
                              hipStream_t stream) {
    const float* sat = (const float*)d_in[0];
    const float* grd = (const float*)d_in[1];
    float* out = (float*)d_out;
    // Single dispatch: prep eliminated (B fragments are contiguous in raw grd),
    // passthrough copies tail-fused. d_ws unused (its 42us poison fill is
    // unconditional harness overhead either way - proven R2).
    corr_k<<<256, 512, 0, stream>>>(sat, grd, out,
                                    (const float4*)sat, (const float4*)grd, (float4*)out);
}